// Round 2
// baseline (365.420 us; speedup 1.0000x reference)
//
#include <hip/hip_runtime.h>

typedef short s16x8 __attribute__((ext_vector_type(8)));
typedef float f32x4 __attribute__((ext_vector_type(4)));
typedef unsigned int u32x2 __attribute__((ext_vector_type(2)));
typedef unsigned short u16;
typedef unsigned int u32;

#define D_MODEL 1024
#define NHEAD   16
#define HD      64
#define TSEQ    2048
#define NB      2
#define MROWS   4096   // B*T

__device__ __forceinline__ u16 f2bf(float f) {
  unsigned u = __builtin_bit_cast(unsigned, f);
  u += 0x7fffu + ((u >> 16) & 1u);
  return (u16)(u >> 16);
}

__device__ __forceinline__ u32 cvtpk(float lo, float hi) {
  u32 r;
  asm("v_cvt_pk_bf16_f32 %0, %1, %2" : "=v"(r) : "v"(lo), "v"(hi));
  return r;
}

__device__ __forceinline__ void gload16(const void* g, void* l) {
  __builtin_amdgcn_global_load_lds((const __attribute__((address_space(1))) void*)g,
                                   (__attribute__((address_space(3))) void*)l,
                                   16, 0, 0);
}

// ---------------- fp32 -> bf16 converts (batched by z) ----------------
__global__ void cvt3(const float* __restrict__ a, const float* __restrict__ b,
                     const float* __restrict__ c, u16* o0, u16* o1, u16* o2, int n4) {
  int i = blockIdx.x * blockDim.x + threadIdx.x;
  if (i >= n4) return;
  const float* in = (blockIdx.y == 0) ? a : (blockIdx.y == 1) ? b : c;
  u16* out = (blockIdx.y == 0) ? o0 : (blockIdx.y == 1) ? o1 : o2;
  float4 v = ((const float4*)in)[i];
  ushort4 o;
  o.x = f2bf(v.x); o.y = f2bf(v.y); o.z = f2bf(v.z); o.w = f2bf(v.w);
  ((ushort4*)out)[i] = o;
}

__global__ void cvt4(const float* __restrict__ a, const float* __restrict__ b,
                     const float* __restrict__ c, const float* __restrict__ d,
                     u16* o0, u16* o1, u16* o2, u16* o3, int n4) {
  int i = blockIdx.x * blockDim.x + threadIdx.x;
  if (i >= n4) return;
  int z = blockIdx.y;
  const float* in = (z == 0) ? a : (z == 1) ? b : (z == 2) ? c : d;
  u16* out = (z == 0) ? o0 : (z == 1) ? o1 : (z == 2) ? o2 : o3;
  float4 v = ((const float4*)in)[i];
  ushort4 o;
  o.x = f2bf(v.x); o.y = f2bf(v.y); o.z = f2bf(v.z); o.w = f2bf(v.w);
  ((ushort4*)out)[i] = o;
}

// ---------------- sum(attn_bias) ----------------
__global__ void bias_sum_k(const float* __restrict__ ab, float* __restrict__ o) {
  float v = ab[threadIdx.x];
#pragma unroll
  for (int m = 32; m >= 1; m >>= 1) v += __shfl_xor(v, m);
  if (threadIdx.x == 0) o[0] = v;
}

// ---------------- GEMM core: C = A*Bt^T + bias, 128x128 tile ----------------
// mode 0: out bf16 (B,H,T,Dh);  mode 1: out bf16 (B,H,Dh,T);  mode 2: out fp32 row-major
#define GEMM_BODY(A_, Bt_, bias_, out_, mode_)                                           \
  constexpr int K = 1024, N = 1024;                                                      \
  int tid = threadIdx.x;                                                                 \
  int wid = tid >> 6, lane = tid & 63;                                                   \
  int l15 = lane & 15, lgp = lane >> 4;                                                  \
  int wr = wid >> 1, wc = wid & 1;                                                       \
  int m0 = blockIdx.y * 128, n0 = blockIdx.x * 128;                                      \
  int r0 = tid & 127, c0 = tid >> 7;                                                     \
  const u16* gA0 = A_ + (size_t)(m0 + r0) * K + c0 * 8;                                  \
  const u16* gA1 = A_ + (size_t)(m0 + r0) * K + (c0 + 2) * 8;                            \
  const u16* gB0 = Bt_ + (size_t)(n0 + r0) * K + c0 * 8;                                 \
  const u16* gB1 = Bt_ + (size_t)(n0 + r0) * K + (c0 + 2) * 8;                           \
  u16* lA0 = &lA[0][0][0] + (size_t)(wid * 64) * 8;                                      \
  u16* lA1 = &lA[0][0][0] + (size_t)(256 + wid * 64) * 8;                                \
  u16* lB0 = &lB[0][0][0] + (size_t)(wid * 64) * 8;                                      \
  u16* lB1 = &lB[0][0][0] + (size_t)(256 + wid * 64) * 8;                                \
  f32x4 acc[4][4];                                                                       \
  _Pragma("unroll") for (int m = 0; m < 4; ++m)                                          \
    _Pragma("unroll") for (int n = 0; n < 4; ++n)                                        \
      acc[m][n] = (f32x4){0.f, 0.f, 0.f, 0.f};                                           \
  for (int k0 = 0; k0 < K; k0 += 32) {                                                   \
    gload16(gA0 + k0, lA0);                                                              \
    gload16(gA1 + k0, lA1);                                                              \
    gload16(gB0 + k0, lB0);                                                              \
    gload16(gB1 + k0, lB1);                                                              \
    __syncthreads();                                                                     \
    s16x8 af[4], bf[4];                                                                  \
    _Pragma("unroll") for (int m = 0; m < 4; ++m)                                        \
      af[m] = *(const s16x8*)&lA[lgp][wr * 64 + m * 16 + l15][0];                        \
    _Pragma("unroll") for (int n = 0; n < 4; ++n)                                        \
      bf[n] = *(const s16x8*)&lB[lgp][wc * 64 + n * 16 + l15][0];                        \
    _Pragma("unroll") for (int m = 0; m < 4; ++m)                                        \
      _Pragma("unroll") for (int n = 0; n < 4; ++n)                                      \
        acc[m][n] = __builtin_amdgcn_mfma_f32_16x16x32_bf16(af[m], bf[n], acc[m][n], 0, 0, 0); \
    __syncthreads();                                                                     \
  }                                                                                      \
  float bvv[4];                                                                          \
  _Pragma("unroll") for (int n = 0; n < 4; ++n)                                          \
    bvv[n] = bias_[n0 + wc * 64 + n * 16 + l15];                                         \
  _Pragma("unroll") for (int m = 0; m < 4; ++m) {                                        \
    int rowb = m0 + wr * 64 + m * 16 + lgp * 4;                                          \
    _Pragma("unroll") for (int n = 0; n < 4; ++n) {                                      \
      int col = n0 + wc * 64 + n * 16 + l15;                                             \
      _Pragma("unroll") for (int r = 0; r < 4; ++r) {                                    \
        int row = rowb + r;                                                              \
        float v = acc[m][n][r] + bvv[n];                                                 \
        if (mode_ == 2) {                                                                \
          ((float*)out_)[(size_t)row * N + col] = v;                                     \
        } else {                                                                         \
          int b = row >> 11, t = row & 2047;                                             \
          int h = col >> 6, d = col & 63;                                                \
          u16 x = f2bf(v);                                                               \
          if (mode_ == 0)                                                                \
            ((u16*)out_)[(((size_t)(b * NHEAD + h) * TSEQ + t) << 6) + d] = x;           \
          else                                                                           \
            ((u16*)out_)[(((size_t)(b * NHEAD + h) * HD + d) << 11) + t] = x;            \
        }                                                                                \
      }                                                                                  \
    }                                                                                    \
  }

__global__ __launch_bounds__(256) void gemm_qkv(const u16* __restrict__ qb, const u16* __restrict__ kb,
                                                const u16* __restrict__ vb,
                                                const u16* __restrict__ Wqb, const u16* __restrict__ Wkb,
                                                const u16* __restrict__ Wvb,
                                                const float* __restrict__ bq, const float* __restrict__ bk,
                                                const float* __restrict__ bv,
                                                u16* Qp, u16* Kp, u16* Vtp) {
  __shared__ __align__(16) u16 lA[4][128][8];
  __shared__ __align__(16) u16 lB[4][128][8];
  int z = blockIdx.z;
  const u16* A = (z == 0) ? qb : (z == 1) ? kb : vb;
  const u16* Bt = (z == 0) ? Wqb : (z == 1) ? Wkb : Wvb;
  const float* bias = (z == 0) ? bq : (z == 1) ? bk : bv;
  u16* out = (z == 0) ? Qp : (z == 1) ? Kp : Vtp;
  int mode = (z == 2) ? 1 : 0;
  GEMM_BODY(A, Bt, bias, out, mode)
}

__global__ __launch_bounds__(256) void gemm_out(const u16* __restrict__ A, const u16* __restrict__ Bt,
                                                const float* __restrict__ bias, float* __restrict__ out) {
  __shared__ __align__(16) u16 lA[4][128][8];
  __shared__ __align__(16) u16 lB[4][128][8];
  GEMM_BODY(A, Bt, bias, out, 2)
}

// ---------------- flash attention, swapped-QK in-register softmax ----------------
// grid: (T/64, B*H), block 256 = 4 waves. Wave w owns q rows [bx*64+w*16, +16).
// Swapped QK^T: S = mfma(K_frag, Q_frag) -> lane holds S[kv = n*16+lgp*4+r][q = l15].
__global__ __launch_bounds__(256, 4) void attn_kernel(const u16* __restrict__ Qp,
                                                      const u16* __restrict__ Kp,
                                                      const u16* __restrict__ Vt,
                                                      const float* __restrict__ frac,
                                                      const float* __restrict__ bsum,
                                                      u16* __restrict__ aout) {
  __shared__ __align__(16) u16 plds[4][16][64];  // per-wave 2KB P tile, XOR-swizzled rows
  int tid = threadIdx.x, wid = tid >> 6, lane = tid & 63;
  int l15 = lane & 15, lgp = lane >> 4;
  int bh = blockIdx.y, b = bh >> 4, h = bh & 15;
  const u16* Qh = Qp + (size_t)bh * TSEQ * HD;
  const u16* Kh = Kp + (size_t)bh * TSEQ * HD;
  const u16* Vh = Vt + (size_t)bh * HD * TSEQ;
  const float* fb = frac + b * TSEQ;
  const float bsc = bsum[0] * 0.125f;  // bias_sum * scale
  int q0 = blockIdx.x * 64 + wid * 16;

  char* pb = (char*)&plds[wid][0][0];
  const int sw = (l15 & 7) << 4;  // row-XOR swizzle (G4: breaks the 128B-stride conflict)

  // Q fragments (B-operand: lane l15 = q col, k = dh slice)
  s16x8 qf[2];
#pragma unroll
  for (int ks = 0; ks < 2; ++ks)
    qf[ks] = *(const s16x8*)(Qh + (size_t)(q0 + l15) * HD + ks * 32 + lgp * 8);

  const float fi = fb[q0 + l15];   // one q-row per lane
  float mrun = -3.0e38f, lrun = 0.f;
  f32x4 o[4];
#pragma unroll
  for (int nd = 0; nd < 4; ++nd) o[nd] = (f32x4){0.f, 0.f, 0.f, 0.f};

  for (int kv0 = 0; kv0 < TSEQ; kv0 += 64) {
    // ---- QK^T (swapped): s[n][r] = S[kv0+n*16+lgp*4+r][q0+l15]
    f32x4 s[4];
#pragma unroll
    for (int n = 0; n < 4; ++n) {
      const u16* kr = Kh + (size_t)(kv0 + n * 16 + l15) * HD + lgp * 8;
      s16x8 kf0 = *(const s16x8*)(kr);
      s16x8 kf1 = *(const s16x8*)(kr + 32);
      s[n] = (f32x4){0.f, 0.f, 0.f, 0.f};
      s[n] = __builtin_amdgcn_mfma_f32_16x16x32_bf16(kf0, qf[0], s[n], 0, 0, 0);
      s[n] = __builtin_amdgcn_mfma_f32_16x16x32_bf16(kf1, qf[1], s[n], 0, 0, 0);
    }

    // ---- logits (overwrite s in place) + row max (in-register + 2 shfl)
    float tmax = -3.0e38f;
#pragma unroll
    for (int n = 0; n < 4; ++n) {
      float4 fj4 = *(const float4*)(fb + kv0 + n * 16 + lgp * 4);
#pragma unroll
      for (int r = 0; r < 4; ++r) {
        float fj = (r == 0) ? fj4.x : (r == 1) ? fj4.y : (r == 2) ? fj4.z : fj4.w;
        float num = fj - fi;
        float den = __builtin_fmaf(fi, fj, 1e-8f);
        float t = __fdividef(num, den);
        float l = __builtin_fmaf(bsc, t, s[n][r] * 0.125f);
        s[n][r] = l;
        tmax = fmaxf(tmax, l);
      }
    }
    tmax = fmaxf(tmax, __shfl_xor(tmax, 16));
    tmax = fmaxf(tmax, __shfl_xor(tmax, 32));

    // ---- defer-max (T13): rescale only when some row grew past THR=8
    bool need = (tmax - mrun) > 8.f;
    float mnew = __any(need) ? fmaxf(mrun, tmax) : mrun;
    bool resc = (mnew != mrun) || __any(need);

    // ---- P = exp(l - mnew), pack to bf16 pairs, row sum
    float ps = 0.f;
    u32 w[4][2];
#pragma unroll
    for (int n = 0; n < 4; ++n) {
#pragma unroll
      for (int s2 = 0; s2 < 2; ++s2) {
        float p0 = __expf(s[n][2 * s2 + 0] - mnew);
        float p1 = __expf(s[n][2 * s2 + 1] - mnew);
        ps += p0 + p1;
        w[n][s2] = cvtpk(p0, p1);
      }
    }
    ps += __shfl_xor(ps, 16);
    ps += __shfl_xor(ps, 32);

    if (resc) {
      float alpha = __expf(mrun - mnew);
      float af[4];
#pragma unroll
      for (int r = 0; r < 4; ++r) af[r] = __shfl(alpha, lgp * 4 + r);  // o rows are q=lgp*4+r
#pragma unroll
      for (int nd = 0; nd < 4; ++nd)
#pragma unroll
        for (int r = 0; r < 4; ++r) o[nd][r] *= af[r];
      lrun = lrun * alpha + ps;
      mrun = mnew;
    } else {
      lrun += ps;
    }

    // ---- P -> LDS (swizzled ds_write_b64, conflict-free) then PV A-frag reads
#pragma unroll
    for (int n = 0; n < 4; ++n) {
      int wo = l15 * 128 + n * 32 + lgp * 8;
      *(u32x2*)(pb + (wo ^ sw)) = (u32x2){w[n][0], w[n][1]};
    }
    s16x8 pf[2];
#pragma unroll
    for (int ks = 0; ks < 2; ++ks) {
      int ro = l15 * 128 + ks * 64 + lgp * 16;
      pf[ks] = *(const s16x8*)(pb + (ro ^ sw));
    }

    // ---- PV: o[nd] += P(16xkv64) * V(kv64 x dh64)
#pragma unroll
    for (int nd = 0; nd < 4; ++nd) {
      const u16* vr = Vh + (size_t)(nd * 16 + l15) * TSEQ + kv0 + lgp * 8;
      s16x8 vf0 = *(const s16x8*)(vr);
      s16x8 vf1 = *(const s16x8*)(vr + 32);
      o[nd] = __builtin_amdgcn_mfma_f32_16x16x32_bf16(pf[0], vf0, o[nd], 0, 0, 0);
      o[nd] = __builtin_amdgcn_mfma_f32_16x16x32_bf16(pf[1], vf1, o[nd], 0, 0, 0);
    }
  }

  // ---- normalize (lrun lives at lane q=l15; o rows are q=lgp*4+r) and store
  float rl[4];
#pragma unroll
  for (int r = 0; r < 4; ++r) {
    float lr = __shfl(lrun, lgp * 4 + r);
    rl[r] = __fdividef(1.f, lr);
  }
#pragma unroll
  for (int nd = 0; nd < 4; ++nd)
#pragma unroll
    for (int r = 0; r < 4; ++r) {
      int q = q0 + lgp * 4 + r;
      aout[((size_t)(b * TSEQ + q)) * D_MODEL + h * HD + nd * 16 + l15] = f2bf(o[nd][r] * rl[r]);
    }
}

extern "C" void kernel_launch(void* const* d_in, const int* in_sizes, int n_in,
                              void* d_out, int out_size, void* d_ws, size_t ws_size,
                              hipStream_t stream) {
  const float* query = (const float*)d_in[0];
  const float* key_  = (const float*)d_in[1];
  const float* value = (const float*)d_in[2];
  const float* frac  = (const float*)d_in[3];
  const float* Wq    = (const float*)d_in[4];
  const float* bq    = (const float*)d_in[5];
  const float* Wk    = (const float*)d_in[6];
  const float* bk    = (const float*)d_in[7];
  const float* Wv    = (const float*)d_in[8];
  const float* bv    = (const float*)d_in[9];
  const float* abias = (const float*)d_in[10];
  const float* Wo    = (const float*)d_in[11];
  const float* bo    = (const float*)d_in[12];

  char* ws = (char*)d_ws;
  size_t off = 0;
  auto alloc = [&](size_t bytes) { char* p = ws + off; off += (bytes + 255) & ~255ULL; return p; };
  const size_t XB = (size_t)MROWS * D_MODEL * 2;
  const size_t WB = (size_t)D_MODEL * D_MODEL * 2;
  u16* qb  = (u16*)alloc(XB);
  u16* kb  = (u16*)alloc(XB);
  u16* vb  = (u16*)alloc(XB);
  u16* Wqb = (u16*)alloc(WB);
  u16* Wkb = (u16*)alloc(WB);
  u16* Wvb = (u16*)alloc(WB);
  u16* Wob = (u16*)alloc(WB);
  float* bsum = (float*)alloc(256);
  u16* Qp  = (u16*)alloc(XB);
  u16* Kp  = (u16*)alloc(XB);
  u16* Vtp = (u16*)alloc(XB);
  u16* AO  = (u16*)alloc(XB);

  const int n4X = MROWS * D_MODEL / 4;
  const int n4W = D_MODEL * D_MODEL / 4;
  cvt3<<<dim3(n4X / 256, 3), dim3(256), 0, stream>>>(query, key_, value, qb, kb, vb, n4X);
  cvt4<<<dim3(n4W / 256, 4), dim3(256), 0, stream>>>(Wq, Wk, Wv, Wo, Wqb, Wkb, Wvb, Wob, n4W);
  bias_sum_k<<<dim3(1), dim3(64), 0, stream>>>(abias, bsum);

  gemm_qkv<<<dim3(D_MODEL / 128, MROWS / 128, 3), dim3(256), 0, stream>>>(
      qb, kb, vb, Wqb, Wkb, Wvb, bq, bk, bv, Qp, Kp, Vtp);

  attn_kernel<<<dim3(TSEQ / 64, NB * NHEAD), dim3(256), 0, stream>>>(Qp, Kp, Vtp, frac, bsum, AO);

  gemm_out<<<dim3(D_MODEL / 128, MROWS / 128), dim3(256), 0, stream>>>(AO, Wob, bo, (float*)d_out);
}

// Round 3
// 240.938 us; speedup vs baseline: 1.5167x; 1.5167x over previous
//
#include <hip/hip_runtime.h>

typedef short s16x8 __attribute__((ext_vector_type(8)));
typedef float f32x4 __attribute__((ext_vector_type(4)));
typedef unsigned int u32x2 __attribute__((ext_vector_type(2)));
typedef unsigned short u16;
typedef unsigned int u32;

#define D_MODEL 1024
#define NHEAD   16
#define HD      64
#define TSEQ    2048
#define NB      2
#define MROWS   4096   // B*T

__device__ __forceinline__ u16 f2bf(float f) {
  unsigned u = __builtin_bit_cast(unsigned, f);
  u += 0x7fffu + ((u >> 16) & 1u);
  return (u16)(u >> 16);
}

__device__ __forceinline__ u32 cvtpk(float lo, float hi) {
  u32 r;
  asm("v_cvt_pk_bf16_f32 %0, %1, %2" : "=v"(r) : "v"(lo), "v"(hi));
  return r;
}

__device__ __forceinline__ float exp2fast(float x) {
#if __has_builtin(__builtin_amdgcn_exp2f)
  return __builtin_amdgcn_exp2f(x);
#else
  return exp2f(x);
#endif
}

__device__ __forceinline__ void gload16(const void* g, void* l) {
  __builtin_amdgcn_global_load_lds((const __attribute__((address_space(1))) void*)g,
                                   (__attribute__((address_space(3))) void*)l,
                                   16, 0, 0);
}

// ---------------- fp32 -> bf16 converts (batched by z) ----------------
__global__ void cvt3(const float* __restrict__ a, const float* __restrict__ b,
                     const float* __restrict__ c, u16* o0, u16* o1, u16* o2, int n4) {
  int i = blockIdx.x * blockDim.x + threadIdx.x;
  if (i >= n4) return;
  const float* in = (blockIdx.y == 0) ? a : (blockIdx.y == 1) ? b : c;
  u16* out = (blockIdx.y == 0) ? o0 : (blockIdx.y == 1) ? o1 : o2;
  float4 v = ((const float4*)in)[i];
  ushort4 o;
  o.x = f2bf(v.x); o.y = f2bf(v.y); o.z = f2bf(v.z); o.w = f2bf(v.w);
  ((ushort4*)out)[i] = o;
}

__global__ void cvt4(const float* __restrict__ a, const float* __restrict__ b,
                     const float* __restrict__ c, const float* __restrict__ d,
                     u16* o0, u16* o1, u16* o2, u16* o3, int n4) {
  int i = blockIdx.x * blockDim.x + threadIdx.x;
  if (i >= n4) return;
  int z = blockIdx.y;
  const float* in = (z == 0) ? a : (z == 1) ? b : (z == 2) ? c : d;
  u16* out = (z == 0) ? o0 : (z == 1) ? o1 : (z == 2) ? o2 : o3;
  float4 v = ((const float4*)in)[i];
  ushort4 o;
  o.x = f2bf(v.x); o.y = f2bf(v.y); o.z = f2bf(v.z); o.w = f2bf(v.w);
  ((ushort4*)out)[i] = o;
}

// ---------------- sum(attn_bias) ----------------
__global__ void bias_sum_k(const float* __restrict__ ab, float* __restrict__ o) {
  float v = ab[threadIdx.x];
#pragma unroll
  for (int m = 32; m >= 1; m >>= 1) v += __shfl_xor(v, m);
  if (threadIdx.x == 0) o[0] = v;
}

// ---------------- GEMM core: C = A*Bt^T + bias, 128x128 tile ----------------
// mode 0: out bf16 (B,H,T,Dh);  mode 1: out bf16 (B,H,Dh,T);  mode 2: out fp32 row-major
#define GEMM_BODY(A_, Bt_, bias_, out_, mode_)                                           \
  constexpr int K = 1024, N = 1024;                                                      \
  int tid = threadIdx.x;                                                                 \
  int wid = tid >> 6, lane = tid & 63;                                                   \
  int l15 = lane & 15, lgp = lane >> 4;                                                  \
  int wr = wid >> 1, wc = wid & 1;                                                       \
  int m0 = blockIdx.y * 128, n0 = blockIdx.x * 128;                                      \
  int r0 = tid & 127, c0 = tid >> 7;                                                     \
  const u16* gA0 = A_ + (size_t)(m0 + r0) * K + c0 * 8;                                  \
  const u16* gA1 = A_ + (size_t)(m0 + r0) * K + (c0 + 2) * 8;                            \
  const u16* gB0 = Bt_ + (size_t)(n0 + r0) * K + c0 * 8;                                 \
  const u16* gB1 = Bt_ + (size_t)(n0 + r0) * K + (c0 + 2) * 8;                           \
  u16* lA0 = &lA[0][0][0] + (size_t)(wid * 64) * 8;                                      \
  u16* lA1 = &lA[0][0][0] + (size_t)(256 + wid * 64) * 8;                                \
  u16* lB0 = &lB[0][0][0] + (size_t)(wid * 64) * 8;                                      \
  u16* lB1 = &lB[0][0][0] + (size_t)(256 + wid * 64) * 8;                                \
  f32x4 acc[4][4];                                                                       \
  _Pragma("unroll") for (int m = 0; m < 4; ++m)                                          \
    _Pragma("unroll") for (int n = 0; n < 4; ++n)                                        \
      acc[m][n] = (f32x4){0.f, 0.f, 0.f, 0.f};                                           \
  for (int k0 = 0; k0 < K; k0 += 32) {                                                   \
    gload16(gA0 + k0, lA0);                                                              \
    gload16(gA1 + k0, lA1);                                                              \
    gload16(gB0 + k0, lB0);                                                              \
    gload16(gB1 + k0, lB1);                                                              \
    __syncthreads();                                                                     \
    s16x8 af[4], bf[4];                                                                  \
    _Pragma("unroll") for (int m = 0; m < 4; ++m)                                        \
      af[m] = *(const s16x8*)&lA[lgp][wr * 64 + m * 16 + l15][0];                        \
    _Pragma("unroll") for (int n = 0; n < 4; ++n)                                        \
      bf[n] = *(const s16x8*)&lB[lgp][wc * 64 + n * 16 + l15][0];                        \
    _Pragma("unroll") for (int m = 0; m < 4; ++m)                                        \
      _Pragma("unroll") for (int n = 0; n < 4; ++n)                                      \
        acc[m][n] = __builtin_amdgcn_mfma_f32_16x16x32_bf16(af[m], bf[n], acc[m][n], 0, 0, 0); \
    __syncthreads();                                                                     \
  }                                                                                      \
  float bvv[4];                                                                          \
  _Pragma("unroll") for (int n = 0; n < 4; ++n)                                          \
    bvv[n] = bias_[n0 + wc * 64 + n * 16 + l15];                                         \
  _Pragma("unroll") for (int m = 0; m < 4; ++m) {                                        \
    int rowb = m0 + wr * 64 + m * 16 + lgp * 4;                                          \
    _Pragma("unroll") for (int n = 0; n < 4; ++n) {                                      \
      int col = n0 + wc * 64 + n * 16 + l15;                                             \
      _Pragma("unroll") for (int r = 0; r < 4; ++r) {                                    \
        int row = rowb + r;                                                              \
        float v = acc[m][n][r] + bvv[n];                                                 \
        if (mode_ == 2) {                                                                \
          ((float*)out_)[(size_t)row * N + col] = v;                                     \
        } else {                                                                         \
          int b = row >> 11, t = row & 2047;                                             \
          int h = col >> 6, d = col & 63;                                                \
          u16 x = f2bf(v);                                                               \
          if (mode_ == 0)                                                                \
            ((u16*)out_)[(((size_t)(b * NHEAD + h) * TSEQ + t) << 6) + d] = x;           \
          else                                                                           \
            ((u16*)out_)[(((size_t)(b * NHEAD + h) * HD + d) << 11) + t] = x;            \
        }                                                                                \
      }                                                                                  \
    }                                                                                    \
  }

__global__ __launch_bounds__(256) void gemm_qkv(const u16* __restrict__ qb, const u16* __restrict__ kb,
                                                const u16* __restrict__ vb,
                                                const u16* __restrict__ Wqb, const u16* __restrict__ Wkb,
                                                const u16* __restrict__ Wvb,
                                                const float* __restrict__ bq, const float* __restrict__ bk,
                                                const float* __restrict__ bv,
                                                u16* Qp, u16* Kp, u16* Vtp) {
  __shared__ __align__(16) u16 lA[4][128][8];
  __shared__ __align__(16) u16 lB[4][128][8];
  int z = blockIdx.z;
  const u16* A = (z == 0) ? qb : (z == 1) ? kb : vb;
  const u16* Bt = (z == 0) ? Wqb : (z == 1) ? Wkb : Wvb;
  const float* bias = (z == 0) ? bq : (z == 1) ? bk : bv;
  u16* out = (z == 0) ? Qp : (z == 1) ? Kp : Vtp;
  int mode = (z == 2) ? 1 : 0;
  GEMM_BODY(A, Bt, bias, out, mode)
}

__global__ __launch_bounds__(256) void gemm_out(const u16* __restrict__ A, const u16* __restrict__ Bt,
                                                const float* __restrict__ bias, float* __restrict__ out) {
  __shared__ __align__(16) u16 lA[4][128][8];
  __shared__ __align__(16) u16 lB[4][128][8];
  GEMM_BODY(A, Bt, bias, out, 2)
}

// ---------------- flash attention: LDS-staged K/V, swapped-QK, speculative softmax ----------------
// grid: (T/128, B*H), block 256 = 4 waves. Wave w owns q rows [bx*128 + w*32, +32) as qm=0,1 subtiles.
// K/V tiles (64 kv x 64 dh) double-buffered in LDS; swizzle: 16B-slot c holds global col8 c^(row&7).
__global__ __launch_bounds__(256, 2) void attn_kernel(const u16* __restrict__ Qp,
                                                      const u16* __restrict__ Kp,
                                                      const u16* __restrict__ Vt,
                                                      const float* __restrict__ frac,
                                                      const float* __restrict__ bsum,
                                                      u16* __restrict__ aout) {
  __shared__ __align__(16) u16 kbuf[2][64 * 64];
  __shared__ __align__(16) u16 vbuf[2][64 * 64];
  __shared__ __align__(16) u16 plds[4][32 * 64];
  const int tid = threadIdx.x, wid = tid >> 6, lane = tid & 63;
  const int l15 = lane & 15, lgp = lane >> 4;
  const int bh = blockIdx.y, b = bh >> 4, h = bh & 15;
  const u16* Qh = Qp + (size_t)bh * TSEQ * HD;
  const u16* Kh = Kp + (size_t)bh * TSEQ * HD;
  const u16* Vh = Vt + (size_t)bh * HD * TSEQ;
  const float* fb = frac + b * TSEQ;
  const float LOG2E = 1.4426950408889634f;
  const float bsc2 = bsum[0] * 0.125f * LOG2E;   // bias_sum * scale * log2(e)
  const float c1 = 0.125f * LOG2E;
  const float THR2 = 24.0f;                      // defer-max threshold (log2 units)
  const int q0 = blockIdx.x * 128 + wid * 32;

  // staging lane constants (pre-swizzled global source, rule #21)
  const int srow = lane >> 3;                    // row within 8-row/issue group
  const int sg8 = ((lane & 7) ^ srow) * 8;       // swizzled col8 * 8 (u16 units)
  const int rbase = wid * 8 + srow;

  // frag-read offsets (u16 units): row l15-based, col slot (ks*4+lgp)^(l15&7)
  const int ofs0 = l15 * 64 + ((lgp ^ (l15 & 7)) * 8);
  const int ofs1 = l15 * 64 + (((4 + lgp) ^ (l15 & 7)) * 8);

  // Q fragments (B-operand: lane l15 = q col, lgp*8 = dh slice)
  s16x8 qf[2][2];
#pragma unroll
  for (int qm = 0; qm < 2; ++qm)
#pragma unroll
    for (int ks = 0; ks < 2; ++ks)
      qf[qm][ks] = *(const s16x8*)(Qh + (size_t)(q0 + qm * 16 + l15) * HD + ks * 32 + lgp * 8);

  float fi[2];
#pragma unroll
  for (int qm = 0; qm < 2; ++qm) fi[qm] = fb[q0 + qm * 16 + l15];

  float m2run[2] = {-1e30f, -1e30f};
  float lsum[2] = {0.f, 0.f};   // per-lane partial (reduced across lgp at the end)
  f32x4 o[2][4];
#pragma unroll
  for (int qm = 0; qm < 2; ++qm)
#pragma unroll
    for (int nd = 0; nd < 4; ++nd) o[qm][nd] = (f32x4){0.f, 0.f, 0.f, 0.f};

  auto stage = [&](int buf, int t) {
    int kv0s = t * 64;
#pragma unroll
    for (int i = 0; i < 2; ++i) {
      int row = i * 32 + rbase;
      gload16(Kh + (size_t)(kv0s + row) * HD + sg8, &kbuf[buf][i * 2048 + wid * 512]);
      gload16(Vh + (size_t)row * TSEQ + kv0s + sg8, &vbuf[buf][i * 2048 + wid * 512]);
    }
  };

  int cur = 0;
  stage(0, 0);
  __syncthreads();

  for (int t = 0; t < TSEQ / 64; ++t) {
    const int kv0 = t * 64;
    if (t + 1 < TSEQ / 64) stage(cur ^ 1, t + 1);

    const u16* kb = &kbuf[cur][0];
    const u16* vb = &vbuf[cur][0];

    // ---- QK^T (swapped): s[qm][n][r] = S[kv0+n*16+lgp*4+r][q0+qm*16+l15]
    f32x4 s[2][4];
#pragma unroll
    for (int n = 0; n < 4; ++n) {
      s16x8 kf0 = *(const s16x8*)(kb + n * 1024 + ofs0);
      s16x8 kf1 = *(const s16x8*)(kb + n * 1024 + ofs1);
#pragma unroll
      for (int qm = 0; qm < 2; ++qm) {
        f32x4 a = (f32x4){0.f, 0.f, 0.f, 0.f};
        a = __builtin_amdgcn_mfma_f32_16x16x32_bf16(kf0, qf[qm][0], a, 0, 0, 0);
        a = __builtin_amdgcn_mfma_f32_16x16x32_bf16(kf1, qf[qm][1], a, 0, 0, 0);
        s[qm][n] = a;
      }
    }

    // ---- logits in log2 domain + per-lane partial max
    float pmax[2] = {-1e30f, -1e30f};
#pragma unroll
    for (int n = 0; n < 4; ++n) {
      float4 fj4 = *(const float4*)(fb + kv0 + n * 16 + lgp * 4);
#pragma unroll
      for (int r = 0; r < 4; ++r) {
        float fj = (r == 0) ? fj4.x : (r == 1) ? fj4.y : (r == 2) ? fj4.z : fj4.w;
#pragma unroll
        for (int qm = 0; qm < 2; ++qm) {
          float num = fj - fi[qm];
          float den = __builtin_fmaf(fi[qm], fj, 1e-8f);
          float tq = __fdividef(num, den);
          float l2 = __builtin_fmaf(bsc2, tq, s[qm][n][r] * c1);
          s[qm][n][r] = l2;
          pmax[qm] = fmaxf(pmax[qm], l2);
        }
      }
    }

    // ---- rare rescale (speculative defer-max: common path has NO shuffles)
    bool need = ((pmax[0] - m2run[0]) > THR2) || ((pmax[1] - m2run[1]) > THR2);
    if (__any(need)) {
#pragma unroll
      for (int qm = 0; qm < 2; ++qm) {
        float tm = fmaxf(pmax[qm], __shfl_xor(pmax[qm], 16));
        tm = fmaxf(tm, __shfl_xor(tm, 32));
        float m2n = fmaxf(m2run[qm], tm);
        float alpha = exp2fast(m2run[qm] - m2n);
        lsum[qm] *= alpha;
        m2run[qm] = m2n;
        float af[4];
#pragma unroll
        for (int r = 0; r < 4; ++r) af[r] = __shfl(alpha, lgp * 4 + r);
#pragma unroll
        for (int nd = 0; nd < 4; ++nd)
#pragma unroll
          for (int r = 0; r < 4; ++r) o[qm][nd][r] *= af[r];
      }
    }

    // ---- P = exp2(l2 - m2run), pack bf16, partial row-sum
    u32 w[2][4][2];
#pragma unroll
    for (int qm = 0; qm < 2; ++qm) {
      float ps = 0.f;
#pragma unroll
      for (int n = 0; n < 4; ++n) {
#pragma unroll
        for (int s2 = 0; s2 < 2; ++s2) {
          float p0 = exp2fast(s[qm][n][2 * s2 + 0] - m2run[qm]);
          float p1 = exp2fast(s[qm][n][2 * s2 + 1] - m2run[qm]);
          ps += p0 + p1;
          w[qm][n][s2] = cvtpk(p0, p1);
        }
      }
      lsum[qm] += ps;
    }

    // ---- P -> per-wave LDS (swizzled, conflict-free) -> A-operand frags
    u16* pw = &plds[wid][0];
#pragma unroll
    for (int qm = 0; qm < 2; ++qm)
#pragma unroll
      for (int n = 0; n < 4; ++n) {
        int idx = (qm * 16 + l15) * 64 + ((n * 16 + lgp * 4) ^ ((l15 & 7) << 3));
        *(u32x2*)(pw + idx) = (u32x2){w[qm][n][0], w[qm][n][1]};
      }
    s16x8 pf[2][2];
#pragma unroll
    for (int qm = 0; qm < 2; ++qm)
#pragma unroll
      for (int ks = 0; ks < 2; ++ks) {
        int idx = (qm * 16 + l15) * 64 + ((ks * 32 + lgp * 8) ^ ((l15 & 7) << 3));
        pf[qm][ks] = *(const s16x8*)(pw + idx);
      }

    // ---- PV: o[qm][nd] += P * V
#pragma unroll
    for (int nd = 0; nd < 4; ++nd) {
      s16x8 vf0 = *(const s16x8*)(vb + nd * 1024 + ofs0);
      s16x8 vf1 = *(const s16x8*)(vb + nd * 1024 + ofs1);
#pragma unroll
      for (int qm = 0; qm < 2; ++qm) {
        o[qm][nd] = __builtin_amdgcn_mfma_f32_16x16x32_bf16(pf[qm][0], vf0, o[qm][nd], 0, 0, 0);
        o[qm][nd] = __builtin_amdgcn_mfma_f32_16x16x32_bf16(pf[qm][1], vf1, o[qm][nd], 0, 0, 0);
      }
    }

    __syncthreads();
    cur ^= 1;
  }

  // ---- finalize: reduce lsum across lgp, broadcast 1/l to o-rows, store bf16
#pragma unroll
  for (int qm = 0; qm < 2; ++qm) {
    float l = lsum[qm];
    l += __shfl_xor(l, 16);
    l += __shfl_xor(l, 32);
    float rl[4];
#pragma unroll
    for (int r = 0; r < 4; ++r) rl[r] = __fdividef(1.f, __shfl(l, lgp * 4 + r));
#pragma unroll
    for (int nd = 0; nd < 4; ++nd)
#pragma unroll
      for (int r = 0; r < 4; ++r) {
        int q = q0 + qm * 16 + lgp * 4 + r;
        aout[((size_t)(b * TSEQ + q)) * D_MODEL + h * HD + nd * 16 + l15] = f2bf(o[qm][nd][r] * rl[r]);
      }
  }
}

extern "C" void kernel_launch(void* const* d_in, const int* in_sizes, int n_in,
                              void* d_out, int out_size, void* d_ws, size_t ws_size,
                              hipStream_t stream) {
  const float* query = (const float*)d_in[0];
  const float* key_  = (const float*)d_in[1];
  const float* value = (const float*)d_in[2];
  const float* frac  = (const float*)d_in[3];
  const float* Wq    = (const float*)d_in[4];
  const float* bq    = (const float*)d_in[5];
  const float* Wk    = (const float*)d_in[6];
  const float* bk    = (const float*)d_in[7];
  const float* Wv    = (const float*)d_in[8];
  const float* bv    = (const float*)d_in[9];
  const float* abias = (const float*)d_in[10];
  const float* Wo    = (const float*)d_in[11];
  const float* bo    = (const float*)d_in[12];

  char* ws = (char*)d_ws;
  size_t off = 0;
  auto alloc = [&](size_t bytes) { char* p = ws + off; off += (bytes + 255) & ~255ULL; return p; };
  const size_t XB = (size_t)MROWS * D_MODEL * 2;
  const size_t WB = (size_t)D_MODEL * D_MODEL * 2;
  u16* qb  = (u16*)alloc(XB);
  u16* kb  = (u16*)alloc(XB);
  u16* vb  = (u16*)alloc(XB);
  u16* Wqb = (u16*)alloc(WB);
  u16* Wkb = (u16*)alloc(WB);
  u16* Wvb = (u16*)alloc(WB);
  u16* Wob = (u16*)alloc(WB);
  float* bsum = (float*)alloc(256);
  u16* Qp  = (u16*)alloc(XB);
  u16* Kp  = (u16*)alloc(XB);
  u16* Vtp = (u16*)alloc(XB);
  u16* AO  = (u16*)alloc(XB);

  const int n4X = MROWS * D_MODEL / 4;
  const int n4W = D_MODEL * D_MODEL / 4;
  cvt3<<<dim3(n4X / 256, 3), dim3(256), 0, stream>>>(query, key_, value, qb, kb, vb, n4X);
  cvt4<<<dim3(n4W / 256, 4), dim3(256), 0, stream>>>(Wq, Wk, Wv, Wo, Wqb, Wkb, Wvb, Wob, n4W);
  bias_sum_k<<<dim3(1), dim3(64), 0, stream>>>(abias, bsum);

  gemm_qkv<<<dim3(D_MODEL / 128, MROWS / 128, 3), dim3(256), 0, stream>>>(
      qb, kb, vb, Wqb, Wkb, Wvb, bq, bk, bv, Qp, Kp, Vtp);

  attn_kernel<<<dim3(TSEQ / 128, NB * NHEAD), dim3(256), 0, stream>>>(Qp, Kp, Vtp, frac, bsum, AO);

  gemm_out<<<dim3(D_MODEL / 128, MROWS / 128), dim3(256), 0, stream>>>(AO, Wob, bo, (float*)d_out);
}

// Round 4
// 192.565 us; speedup vs baseline: 1.8976x; 1.2512x over previous
//
#include <hip/hip_runtime.h>

typedef short s16x8 __attribute__((ext_vector_type(8)));
typedef float f32x4 __attribute__((ext_vector_type(4)));
typedef unsigned int u32x2 __attribute__((ext_vector_type(2)));
typedef unsigned short u16;
typedef unsigned int u32;

#define D_MODEL 1024
#define NHEAD   16
#define HD      64
#define TSEQ    2048
#define NB      2
#define MROWS   4096   // B*T

#define LOG2E 1.4426950408889634f
#define QSCALE (0.125f * LOG2E)   // folded into Q projection epilogue

__device__ __forceinline__ u16 f2bf(float f) {
  unsigned u = __builtin_bit_cast(unsigned, f);
  u += 0x7fffu + ((u >> 16) & 1u);
  return (u16)(u >> 16);
}

__device__ __forceinline__ u32 cvtpk(float lo, float hi) {
  u32 r;
  asm("v_cvt_pk_bf16_f32 %0, %1, %2" : "=v"(r) : "v"(lo), "v"(hi));
  return r;
}

__device__ __forceinline__ float exp2fast(float x) {
#if __has_builtin(__builtin_amdgcn_exp2f)
  return __builtin_amdgcn_exp2f(x);
#else
  return exp2f(x);
#endif
}

__device__ __forceinline__ float rcpfast(float x) {
#if __has_builtin(__builtin_amdgcn_rcpf)
  return __builtin_amdgcn_rcpf(x);
#else
  return 1.f / x;
#endif
}

__device__ __forceinline__ void gload16(const void* g, void* l) {
  __builtin_amdgcn_global_load_lds((const __attribute__((address_space(1))) void*)g,
                                   (__attribute__((address_space(3))) void*)l,
                                   16, 0, 0);
}

// ---------------- fp32 -> bf16 converts (batched by z) ----------------
__global__ void cvt3(const float* __restrict__ a, const float* __restrict__ b,
                     const float* __restrict__ c, u16* o0, u16* o1, u16* o2, int n4) {
  int i = blockIdx.x * blockDim.x + threadIdx.x;
  if (i >= n4) return;
  const float* in = (blockIdx.y == 0) ? a : (blockIdx.y == 1) ? b : c;
  u16* out = (blockIdx.y == 0) ? o0 : (blockIdx.y == 1) ? o1 : o2;
  float4 v = ((const float4*)in)[i];
  ushort4 o;
  o.x = f2bf(v.x); o.y = f2bf(v.y); o.z = f2bf(v.z); o.w = f2bf(v.w);
  ((ushort4*)out)[i] = o;
}

__global__ void cvt4(const float* __restrict__ a, const float* __restrict__ b,
                     const float* __restrict__ c, const float* __restrict__ d,
                     u16* o0, u16* o1, u16* o2, u16* o3, int n4) {
  int i = blockIdx.x * blockDim.x + threadIdx.x;
  if (i >= n4) return;
  int z = blockIdx.y;
  const float* in = (z == 0) ? a : (z == 1) ? b : (z == 2) ? c : d;
  u16* out = (z == 0) ? o0 : (z == 1) ? o1 : (z == 2) ? o2 : o3;
  float4 v = ((const float4*)in)[i];
  ushort4 o;
  o.x = f2bf(v.x); o.y = f2bf(v.y); o.z = f2bf(v.z); o.w = f2bf(v.w);
  ((ushort4*)out)[i] = o;
}

// ---------------- sum(attn_bias) ----------------
__global__ void bias_sum_k(const float* __restrict__ ab, float* __restrict__ o) {
  float v = ab[threadIdx.x];
#pragma unroll
  for (int m = 32; m >= 1; m >>= 1) v += __shfl_xor(v, m);
  if (threadIdx.x == 0) o[0] = v;
}

// ---------------- GEMM core: C = (A*Bt^T + bias)*oscale, 128x128 tile ----------------
// mode 0: out bf16 (B,H,T,Dh);  mode 1: out bf16 (B,H,Dh,T);  mode 2: out fp32 row-major
#define GEMM_BODY(A_, Bt_, bias_, out_, mode_, oscale_)                                  \
  constexpr int K = 1024, N = 1024;                                                      \
  int tid = threadIdx.x;                                                                 \
  int wid = tid >> 6, lane = tid & 63;                                                   \
  int l15 = lane & 15, lgp = lane >> 4;                                                  \
  int wr = wid >> 1, wc = wid & 1;                                                       \
  int m0 = blockIdx.y * 128, n0 = blockIdx.x * 128;                                      \
  int r0 = tid & 127, c0 = tid >> 7;                                                     \
  const u16* gA0 = A_ + (size_t)(m0 + r0) * K + c0 * 8;                                  \
  const u16* gA1 = A_ + (size_t)(m0 + r0) * K + (c0 + 2) * 8;                            \
  const u16* gB0 = Bt_ + (size_t)(n0 + r0) * K + c0 * 8;                                 \
  const u16* gB1 = Bt_ + (size_t)(n0 + r0) * K + (c0 + 2) * 8;                           \
  u16* lA0 = &lA[0][0][0] + (size_t)(wid * 64) * 8;                                      \
  u16* lA1 = &lA[0][0][0] + (size_t)(256 + wid * 64) * 8;                                \
  u16* lB0 = &lB[0][0][0] + (size_t)(wid * 64) * 8;                                      \
  u16* lB1 = &lB[0][0][0] + (size_t)(256 + wid * 64) * 8;                                \
  f32x4 acc[4][4];                                                                       \
  _Pragma("unroll") for (int m = 0; m < 4; ++m)                                          \
    _Pragma("unroll") for (int n = 0; n < 4; ++n)                                        \
      acc[m][n] = (f32x4){0.f, 0.f, 0.f, 0.f};                                           \
  for (int k0 = 0; k0 < K; k0 += 32) {                                                   \
    gload16(gA0 + k0, lA0);                                                              \
    gload16(gA1 + k0, lA1);                                                              \
    gload16(gB0 + k0, lB0);                                                              \
    gload16(gB1 + k0, lB1);                                                              \
    __syncthreads();                                                                     \
    s16x8 af[4], bf[4];                                                                  \
    _Pragma("unroll") for (int m = 0; m < 4; ++m)                                        \
      af[m] = *(const s16x8*)&lA[lgp][wr * 64 + m * 16 + l15][0];                        \
    _Pragma("unroll") for (int n = 0; n < 4; ++n)                                        \
      bf[n] = *(const s16x8*)&lB[lgp][wc * 64 + n * 16 + l15][0];                        \
    _Pragma("unroll") for (int m = 0; m < 4; ++m)                                        \
      _Pragma("unroll") for (int n = 0; n < 4; ++n)                                      \
        acc[m][n] = __builtin_amdgcn_mfma_f32_16x16x32_bf16(af[m], bf[n], acc[m][n], 0, 0, 0); \
    __syncthreads();                                                                     \
  }                                                                                      \
  float bvv[4];                                                                          \
  _Pragma("unroll") for (int n = 0; n < 4; ++n)                                          \
    bvv[n] = bias_[n0 + wc * 64 + n * 16 + l15];                                         \
  _Pragma("unroll") for (int m = 0; m < 4; ++m) {                                        \
    int rowb = m0 + wr * 64 + m * 16 + lgp * 4;                                          \
    _Pragma("unroll") for (int n = 0; n < 4; ++n) {                                      \
      int col = n0 + wc * 64 + n * 16 + l15;                                             \
      _Pragma("unroll") for (int r = 0; r < 4; ++r) {                                    \
        int row = rowb + r;                                                              \
        float v = (acc[m][n][r] + bvv[n]) * oscale_;                                     \
        if (mode_ == 2) {                                                                \
          ((float*)out_)[(size_t)row * N + col] = v;                                     \
        } else {                                                                         \
          int b = row >> 11, t = row & 2047;                                             \
          int h = col >> 6, d = col & 63;                                                \
          u16 x = f2bf(v);                                                               \
          if (mode_ == 0)                                                                \
            ((u16*)out_)[(((size_t)(b * NHEAD + h) * TSEQ + t) << 6) + d] = x;           \
          else                                                                           \
            ((u16*)out_)[(((size_t)(b * NHEAD + h) * HD + d) << 11) + t] = x;            \
        }                                                                                \
      }                                                                                  \
    }                                                                                    \
  }

__global__ __launch_bounds__(256) void gemm_qkv(const u16* __restrict__ qb, const u16* __restrict__ kb,
                                                const u16* __restrict__ vb,
                                                const u16* __restrict__ Wqb, const u16* __restrict__ Wkb,
                                                const u16* __restrict__ Wvb,
                                                const float* __restrict__ bq, const float* __restrict__ bk,
                                                const float* __restrict__ bv,
                                                u16* Qp, u16* Kp, u16* Vtp) {
  __shared__ __align__(16) u16 lA[4][128][8];
  __shared__ __align__(16) u16 lB[4][128][8];
  int z = blockIdx.z;
  const u16* A = (z == 0) ? qb : (z == 1) ? kb : vb;
  const u16* Bt = (z == 0) ? Wqb : (z == 1) ? Wkb : Wvb;
  const float* bias = (z == 0) ? bq : (z == 1) ? bk : bv;
  u16* out = (z == 0) ? Qp : (z == 1) ? Kp : Vtp;
  int mode = (z == 2) ? 1 : 0;
  float oscale = (z == 0) ? QSCALE : 1.0f;   // fold softmax scale*log2e into Q
  GEMM_BODY(A, Bt, bias, out, mode, oscale)
}

__global__ __launch_bounds__(256) void gemm_out(const u16* __restrict__ A, const u16* __restrict__ Bt,
                                                const float* __restrict__ bias, float* __restrict__ out) {
  __shared__ __align__(16) u16 lA[4][128][8];
  __shared__ __align__(16) u16 lB[4][128][8];
  GEMM_BODY(A, Bt, bias, out, 2, 1.0f)
}

// ---------------- flash attention: LDS-staged K/V, swapped-QK, speculative softmax ----------------
// grid: (T/64, B*H), block 256 = 4 waves. Wave w owns 16 q rows [bx*64 + w*16, +16).
// K/V tiles (64 kv x 64 dh) double-buffered in LDS; swizzle: 16B-slot c holds global col8 c^(row&7).
// Q arrives pre-scaled by 0.125*log2e, so QK^T output is already the log2-domain logit base.
__global__ __launch_bounds__(256, 4) void attn_kernel(const u16* __restrict__ Qp,
                                                      const u16* __restrict__ Kp,
                                                      const u16* __restrict__ Vt,
                                                      const float* __restrict__ frac,
                                                      const float* __restrict__ bsum,
                                                      u16* __restrict__ aout) {
  __shared__ __align__(16) u16 kbuf[2][64 * 64];
  __shared__ __align__(16) u16 vbuf[2][64 * 64];
  __shared__ __align__(16) u16 plds[4][16 * 64];
  const int tid = threadIdx.x, wid = tid >> 6, lane = tid & 63;
  const int l15 = lane & 15, lgp = lane >> 4;
  const int bh = blockIdx.y, b = bh >> 4, h = bh & 15;
  const u16* Qh = Qp + (size_t)bh * TSEQ * HD;
  const u16* Kh = Kp + (size_t)bh * TSEQ * HD;
  const u16* Vh = Vt + (size_t)bh * HD * TSEQ;
  const float* fb = frac + b * TSEQ;
  const float bs = bsum[0] * 0.125f * LOG2E;   // bias_sum * scale * log2e
  const float THR2 = 24.0f;                    // defer-max threshold (log2 units)
  const int q0 = blockIdx.x * 64 + wid * 16;

  // staging lane constants (pre-swizzled global source, rule #21)
  const int srow = lane >> 3;
  const int sg8 = ((lane & 7) ^ srow) * 8;
  const int rbase = wid * 8 + srow;

  // frag-read offsets (u16 units)
  const int ofs0 = l15 * 64 + ((lgp ^ (l15 & 7)) * 8);
  const int ofs1 = l15 * 64 + (((4 + lgp) ^ (l15 & 7)) * 8);

  // Q fragments (B-operand: lane l15 = q col, lgp*8 = dh slice)
  s16x8 qf[2];
#pragma unroll
  for (int ks = 0; ks < 2; ++ks)
    qf[ks] = *(const s16x8*)(Qh + (size_t)(q0 + l15) * HD + ks * 32 + lgp * 8);

  const float fi = fb[q0 + l15];
  const float nbfi = -bs * fi;
  float m2run = -1e30f;
  float lsum = 0.f;   // per-lane partial (reduced across lgp at the end)
  f32x4 o[4];
#pragma unroll
  for (int nd = 0; nd < 4; ++nd) o[nd] = (f32x4){0.f, 0.f, 0.f, 0.f};

  auto stage = [&](int buf, int t) {
    int kv0s = t * 64;
#pragma unroll
    for (int i = 0; i < 2; ++i) {
      int row = i * 32 + rbase;
      gload16(Kh + (size_t)(kv0s + row) * HD + sg8, &kbuf[buf][i * 2048 + wid * 512]);
      gload16(Vh + (size_t)row * TSEQ + kv0s + sg8, &vbuf[buf][i * 2048 + wid * 512]);
    }
  };

  int cur = 0;
  stage(0, 0);
  float4 fj_cur[4], fj_nxt[4];
#pragma unroll
  for (int n = 0; n < 4; ++n) fj_cur[n] = *(const float4*)(fb + n * 16 + lgp * 4);
  __syncthreads();

  for (int t = 0; t < TSEQ / 64; ++t) {
    const bool more = (t + 1 < TSEQ / 64);
    if (more) {
      stage(cur ^ 1, t + 1);
#pragma unroll
      for (int n = 0; n < 4; ++n)
        fj_nxt[n] = *(const float4*)(fb + (t + 1) * 64 + n * 16 + lgp * 4);
    }

    const u16* kb = &kbuf[cur][0];
    const u16* vb = &vbuf[cur][0];

    // ---- QK^T (swapped): s[n][r] = S_log2[kv = t*64+n*16+lgp*4+r][q0+l15]
    f32x4 s[4];
#pragma unroll
    for (int n = 0; n < 4; ++n) {
      s16x8 kf0 = *(const s16x8*)(kb + n * 1024 + ofs0);
      s16x8 kf1 = *(const s16x8*)(kb + n * 1024 + ofs1);
      f32x4 a = (f32x4){0.f, 0.f, 0.f, 0.f};
      a = __builtin_amdgcn_mfma_f32_16x16x32_bf16(kf0, qf[0], a, 0, 0, 0);
      a = __builtin_amdgcn_mfma_f32_16x16x32_bf16(kf1, qf[1], a, 0, 0, 0);
      s[n] = a;
    }

    // ---- logits (log2 domain): l2 = s + bs*(fj-fi)/(fi*fj+eps)
    float pmax = -1e30f;
#pragma unroll
    for (int n = 0; n < 4; ++n) {
#pragma unroll
      for (int r = 0; r < 4; ++r) {
        float fj = (r == 0) ? fj_cur[n].x : (r == 1) ? fj_cur[n].y : (r == 2) ? fj_cur[n].z : fj_cur[n].w;
        float num = __builtin_fmaf(bs, fj, nbfi);
        float den = __builtin_fmaf(fi, fj, 1e-8f);
        float l2 = __builtin_fmaf(num, rcpfast(den), s[n][r]);
        s[n][r] = l2;
        pmax = fmaxf(pmax, l2);
      }
    }

    // ---- rare rescale (speculative defer-max: common path has NO shuffles)
    if (__any((pmax - m2run) > THR2)) {
      float tm = fmaxf(pmax, __shfl_xor(pmax, 16));
      tm = fmaxf(tm, __shfl_xor(tm, 32));
      float m2n = fmaxf(m2run, tm);
      float alpha = exp2fast(m2run - m2n);
      lsum *= alpha;
      m2run = m2n;
      float af[4];
#pragma unroll
      for (int r = 0; r < 4; ++r) af[r] = __shfl(alpha, lgp * 4 + r);
#pragma unroll
      for (int nd = 0; nd < 4; ++nd)
#pragma unroll
        for (int r = 0; r < 4; ++r) o[nd][r] *= af[r];
    }

    // ---- P = exp2(l2 - m2run), pack bf16, partial row-sum
    u32 w[4][2];
    {
      float ps = 0.f;
#pragma unroll
      for (int n = 0; n < 4; ++n) {
#pragma unroll
        for (int s2 = 0; s2 < 2; ++s2) {
          float p0 = exp2fast(s[n][2 * s2 + 0] - m2run);
          float p1 = exp2fast(s[n][2 * s2 + 1] - m2run);
          ps += p0 + p1;
          w[n][s2] = cvtpk(p0, p1);
        }
      }
      lsum += ps;
    }

    // ---- P -> per-wave LDS (swizzled, conflict-free) -> A-operand frags
    u16* pw = &plds[wid][0];
#pragma unroll
    for (int n = 0; n < 4; ++n) {
      int idx = l15 * 64 + ((n * 16 + lgp * 4) ^ ((l15 & 7) << 3));
      *(u32x2*)(pw + idx) = (u32x2){w[n][0], w[n][1]};
    }
    s16x8 pf[2];
#pragma unroll
    for (int ks = 0; ks < 2; ++ks) {
      int idx = l15 * 64 + ((ks * 32 + lgp * 8) ^ ((l15 & 7) << 3));
      pf[ks] = *(const s16x8*)(pw + idx);
    }

    // ---- PV: o[nd] += P * V
#pragma unroll
    for (int nd = 0; nd < 4; ++nd) {
      s16x8 vf0 = *(const s16x8*)(vb + nd * 1024 + ofs0);
      s16x8 vf1 = *(const s16x8*)(vb + nd * 1024 + ofs1);
      o[nd] = __builtin_amdgcn_mfma_f32_16x16x32_bf16(pf[0], vf0, o[nd], 0, 0, 0);
      o[nd] = __builtin_amdgcn_mfma_f32_16x16x32_bf16(pf[1], vf1, o[nd], 0, 0, 0);
    }

    __syncthreads();
    cur ^= 1;
    if (more) {
#pragma unroll
      for (int n = 0; n < 4; ++n) fj_cur[n] = fj_nxt[n];
    }
  }

  // ---- finalize: reduce lsum across lgp, broadcast 1/l to o-rows, store bf16
  {
    float l = lsum;
    l += __shfl_xor(l, 16);
    l += __shfl_xor(l, 32);
    float rl[4];
#pragma unroll
    for (int r = 0; r < 4; ++r) rl[r] = __fdividef(1.f, __shfl(l, lgp * 4 + r));
#pragma unroll
    for (int nd = 0; nd < 4; ++nd)
#pragma unroll
      for (int r = 0; r < 4; ++r) {
        int q = q0 + lgp * 4 + r;
        aout[((size_t)(b * TSEQ + q)) * D_MODEL + h * HD + nd * 16 + l15] = f2bf(o[nd][r] * rl[r]);
      }
  }
}

extern "C" void kernel_launch(void* const* d_in, const int* in_sizes, int n_in,
                              void* d_out, int out_size, void* d_ws, size_t ws_size,
                              hipStream_t stream) {
  const float* query = (const float*)d_in[0];
  const float* key_  = (const float*)d_in[1];
  const float* value = (const float*)d_in[2];
  const float* frac  = (const float*)d_in[3];
  const float* Wq    = (const float*)d_in[4];
  const float* bq    = (const float*)d_in[5];
  const float* Wk    = (const float*)d_in[6];
  const float* bk    = (const float*)d_in[7];
  const float* Wv    = (const float*)d_in[8];
  const float* bv    = (const float*)d_in[9];
  const float* abias = (const float*)d_in[10];
  const float* Wo    = (const float*)d_in[11];
  const float* bo    = (const float*)d_in[12];

  char* ws = (char*)d_ws;
  size_t off = 0;
  auto alloc = [&](size_t bytes) { char* p = ws + off; off += (bytes + 255) & ~255ULL; return p; };
  const size_t XB = (size_t)MROWS * D_MODEL * 2;
  const size_t WB = (size_t)D_MODEL * D_MODEL * 2;
  u16* qb  = (u16*)alloc(XB);
  u16* kb  = (u16*)alloc(XB);
  u16* vb  = (u16*)alloc(XB);
  u16* Wqb = (u16*)alloc(WB);
  u16* Wkb = (u16*)alloc(WB);
  u16* Wvb = (u16*)alloc(WB);
  u16* Wob = (u16*)alloc(WB);
  float* bsum = (float*)alloc(256);
  u16* Qp  = (u16*)alloc(XB);
  u16* Kp  = (u16*)alloc(XB);
  u16* Vtp = (u16*)alloc(XB);
  u16* AO  = (u16*)alloc(XB);

  const int n4X = MROWS * D_MODEL / 4;
  const int n4W = D_MODEL * D_MODEL / 4;
  cvt3<<<dim3(n4X / 256, 3), dim3(256), 0, stream>>>(query, key_, value, qb, kb, vb, n4X);
  cvt4<<<dim3(n4W / 256, 4), dim3(256), 0, stream>>>(Wq, Wk, Wv, Wo, Wqb, Wkb, Wvb, Wob, n4W);
  bias_sum_k<<<dim3(1), dim3(64), 0, stream>>>(abias, bsum);

  gemm_qkv<<<dim3(D_MODEL / 128, MROWS / 128, 3), dim3(256), 0, stream>>>(
      qb, kb, vb, Wqb, Wkb, Wvb, bq, bk, bv, Qp, Kp, Vtp);

  attn_kernel<<<dim3(TSEQ / 64, NB * NHEAD), dim3(256), 0, stream>>>(Qp, Kp, Vtp, frac, bsum, AO);

  gemm_out<<<dim3(D_MODEL / 128, MROWS / 128), dim3(256), 0, stream>>>(AO, Wob, bo, (float*)d_out);
}

// Round 5
// 184.826 us; speedup vs baseline: 1.9771x; 1.0419x over previous
//
#include <hip/hip_runtime.h>

typedef short s16x8 __attribute__((ext_vector_type(8)));
typedef float f32x4 __attribute__((ext_vector_type(4)));
typedef unsigned int u32x2 __attribute__((ext_vector_type(2)));
typedef unsigned short u16;
typedef unsigned int u32;

#define D_MODEL 1024
#define NHEAD   16
#define HD      64
#define TSEQ    2048
#define NB      2
#define MROWS   4096   // B*T

#define LOG2E 1.4426950408889634f
#define QSCALE (0.125f * LOG2E)   // folded into Q projection epilogue

__device__ __forceinline__ u16 f2bf(float f) {
  unsigned u = __builtin_bit_cast(unsigned, f);
  u += 0x7fffu + ((u >> 16) & 1u);
  return (u16)(u >> 16);
}

__device__ __forceinline__ u32 cvtpk(float lo, float hi) {
  u32 r;
  asm("v_cvt_pk_bf16_f32 %0, %1, %2" : "=v"(r) : "v"(lo), "v"(hi));
  return r;
}

__device__ __forceinline__ float exp2fast(float x) {
#if __has_builtin(__builtin_amdgcn_exp2f)
  return __builtin_amdgcn_exp2f(x);
#else
  return exp2f(x);
#endif
}

__device__ __forceinline__ float rcpfast(float x) {
#if __has_builtin(__builtin_amdgcn_rcpf)
  return __builtin_amdgcn_rcpf(x);
#else
  return 1.f / x;
#endif
}

__device__ __forceinline__ void gload16(const void* g, void* l) {
  __builtin_amdgcn_global_load_lds((const __attribute__((address_space(1))) void*)g,
                                   (__attribute__((address_space(3))) void*)l,
                                   16, 0, 0);
}

// ---------------- fused fp32->bf16 converts + bias_sum (one dispatch) ----------------
// grid: 16385 blocks x 256. Blocks 0..16383 convert 4 float4 regions; block 16384 sums attn_bias.
__global__ void cvt_all(const float* __restrict__ q, const float* __restrict__ k,
                        const float* __restrict__ v, const float* __restrict__ wq,
                        const float* __restrict__ wk, const float* __restrict__ wv,
                        const float* __restrict__ wo, const float* __restrict__ ab,
                        u16* qb, u16* kb, u16* vb, u16* wqb, u16* wkb, u16* wvb, u16* wob,
                        float* bsum) {
  if (blockIdx.x == 16384) {
    if (threadIdx.x < 64) {
      float s = ab[threadIdx.x];
#pragma unroll
      for (int m = 32; m >= 1; m >>= 1) s += __shfl_xor(s, m);
      if (threadIdx.x == 0) bsum[0] = s * 0.125f * LOG2E;  // pre-fold scale*log2e
    }
    return;
  }
  int i = blockIdx.x * 256 + threadIdx.x;   // float4 index
  const float* src; u16* dst; int off;
  if (i < 3 * 1048576) {
    int t = i >> 20; off = i & 1048575;
    src = (t == 0) ? q : (t == 1) ? k : v;
    dst = (t == 0) ? qb : (t == 1) ? kb : vb;
  } else {
    int j = i - 3 * 1048576;
    int t = j >> 18; off = j & 262143;
    src = (t == 0) ? wq : (t == 1) ? wk : (t == 2) ? wv : wo;
    dst = (t == 0) ? wqb : (t == 1) ? wkb : (t == 2) ? wvb : wob;
  }
  float4 x = ((const float4*)src)[off];
  ushort4 o;
  o.x = f2bf(x.x); o.y = f2bf(x.y); o.z = f2bf(x.z); o.w = f2bf(x.w);
  ((ushort4*)dst)[off] = o;
}

// ---------------- double-buffered GEMM core: C = (A*Bt^T + bias)*oscale ----------------
// BM x BN tile, 4 waves in WM x WN grid, K-step 32, one barrier per step.
// mode 0: out bf16 (B,H,T,Dh);  mode 1: out bf16 (B,H,Dh,T);  mode 2: out fp32 row-major
template <int BM, int BN, int WN>
__device__ __forceinline__ void gemm_core(const u16* __restrict__ A, const u16* __restrict__ Bt,
                                          const float* __restrict__ bias, void* __restrict__ out,
                                          float oscale, int mode, u16* lds) {
  constexpr int K = 1024, N = 1024;
  constexpr int WM = 4 / WN;
  constexpr int WTM = BM / WM, WTN = BN / WN;
  constexpr int MR = WTM / 16, NR = WTN / 16;
  constexpr int ASZ = BM * 32, BSZ = BN * 32;        // u16 per K-step buffer
  constexpr int AISS = ASZ / 2048, BISS = BSZ / 2048; // gload16 issues (256 thr x 8 u16)
  u16* lA = lds;                // [2][ASZ]
  u16* lB = lds + 2 * ASZ;      // [2][BSZ]

  const int tid = threadIdx.x;
  const int wid = tid >> 6, lane = tid & 63;
  const int l15 = lane & 15, lgp = lane >> 4;
  const int wr = wid / WN, wc = wid % WN;
  const int m0 = blockIdx.y * BM, n0 = blockIdx.x * BN;

  const u16* gA[AISS];
  const u16* gB[BISS];
#pragma unroll
  for (int i = 0; i < AISS; ++i) {
    int tp = i * 256 + tid, row = tp % BM, kc = tp / BM;
    gA[i] = A + (size_t)(m0 + row) * K + kc * 8;
  }
#pragma unroll
  for (int i = 0; i < BISS; ++i) {
    int tp = i * 256 + tid, row = tp % BN, kc = tp / BN;
    gB[i] = Bt + (size_t)(n0 + row) * K + kc * 8;
  }

  f32x4 acc[MR][NR];
#pragma unroll
  for (int m = 0; m < MR; ++m)
#pragma unroll
    for (int n = 0; n < NR; ++n) acc[m][n] = (f32x4){0.f, 0.f, 0.f, 0.f};

  auto stage = [&](int buf, int k0) {
#pragma unroll
    for (int i = 0; i < AISS; ++i)
      gload16(gA[i] + k0, lA + buf * ASZ + (i * 256 + tid) * 8);
#pragma unroll
    for (int i = 0; i < BISS; ++i)
      gload16(gB[i] + k0, lB + buf * BSZ + (i * 256 + tid) * 8);
  };

  int cur = 0;
  stage(0, 0);
  __syncthreads();
  for (int k0 = 0; k0 < K; k0 += 32) {
    if (k0 + 32 < K) stage(cur ^ 1, k0 + 32);
    const u16* a = lA + cur * ASZ;
    const u16* b = lB + cur * BSZ;
    s16x8 af[MR], bf[NR];
#pragma unroll
    for (int m = 0; m < MR; ++m)
      af[m] = *(const s16x8*)(a + lgp * BM * 8 + (wr * WTM + m * 16 + l15) * 8);
#pragma unroll
    for (int n = 0; n < NR; ++n)
      bf[n] = *(const s16x8*)(b + lgp * BN * 8 + (wc * WTN + n * 16 + l15) * 8);
    __builtin_amdgcn_s_setprio(1);
#pragma unroll
    for (int m = 0; m < MR; ++m)
#pragma unroll
      for (int n = 0; n < NR; ++n)
        acc[m][n] = __builtin_amdgcn_mfma_f32_16x16x32_bf16(af[m], bf[n], acc[m][n], 0, 0, 0);
    __builtin_amdgcn_s_setprio(0);
    __syncthreads();
    cur ^= 1;
  }

  float bvv[NR];
#pragma unroll
  for (int n = 0; n < NR; ++n) bvv[n] = bias[n0 + wc * WTN + n * 16 + l15];

#pragma unroll
  for (int m = 0; m < MR; ++m) {
    int rowb = m0 + wr * WTM + m * 16 + lgp * 4;
#pragma unroll
    for (int n = 0; n < NR; ++n) {
      int col = n0 + wc * WTN + n * 16 + l15;
#pragma unroll
      for (int r = 0; r < 4; ++r) {
        int row = rowb + r;
        float vv = (acc[m][n][r] + bvv[n]) * oscale;
        if (mode == 2) {
          ((float*)out)[(size_t)row * N + col] = vv;
        } else {
          int b = row >> 11, t = row & 2047;
          int h = col >> 6, d = col & 63;
          u16 x = f2bf(vv);
          if (mode == 0)
            ((u16*)out)[(((size_t)(b * NHEAD + h) * TSEQ + t) << 6) + d] = x;
          else
            ((u16*)out)[(((size_t)(b * NHEAD + h) * HD + d) << 11) + t] = x;
        }
      }
    }
  }
}

__global__ __launch_bounds__(256) void gemm_qkv(const u16* __restrict__ qb, const u16* __restrict__ kb,
                                                const u16* __restrict__ vb,
                                                const u16* __restrict__ Wqb, const u16* __restrict__ Wkb,
                                                const u16* __restrict__ Wvb,
                                                const float* __restrict__ bq, const float* __restrict__ bk,
                                                const float* __restrict__ bv,
                                                u16* Qp, u16* Kp, u16* Vtp) {
  __shared__ __align__(16) u16 lds[2 * 128 * 32 * 2];   // 32 KB
  int z = blockIdx.z;
  const u16* A  = (z == 0) ? qb : (z == 1) ? kb : vb;
  const u16* Bt = (z == 0) ? Wqb : (z == 1) ? Wkb : Wvb;
  const float* bias = (z == 0) ? bq : (z == 1) ? bk : bv;
  u16* out = (z == 0) ? Qp : (z == 1) ? Kp : Vtp;
  int mode = (z == 2) ? 1 : 0;
  float oscale = (z == 0) ? QSCALE : 1.0f;
  gemm_core<128, 128, 2>(A, Bt, bias, out, oscale, mode, lds);
}

__global__ __launch_bounds__(256) void gemm_out(const u16* __restrict__ A, const u16* __restrict__ Bt,
                                                const float* __restrict__ bias, float* __restrict__ out) {
  __shared__ __align__(16) u16 lds[2 * 64 * 32 + 2 * 128 * 32];   // 24 KB
  gemm_core<64, 128, 4>(A, Bt, bias, out, 1.0f, 2, lds);
}

// ---------------- flash attention: LDS-staged K/V, swapped-QK, speculative softmax ----------------
// grid: (T/64, B*H), block 256 = 4 waves. Wave w owns 16 q rows [bx*64 + w*16, +16).
// K/V tiles (64 kv x 64 dh) double-buffered in LDS; swizzle: 16B-slot c holds global col8 c^(row&7).
// Q arrives pre-scaled by 0.125*log2e; bsum arrives pre-scaled likewise.
__global__ __launch_bounds__(256, 4) void attn_kernel(const u16* __restrict__ Qp,
                                                      const u16* __restrict__ Kp,
                                                      const u16* __restrict__ Vt,
                                                      const float* __restrict__ frac,
                                                      const float* __restrict__ bsum,
                                                      u16* __restrict__ aout) {
  __shared__ __align__(16) u16 kbuf[2][64 * 64];
  __shared__ __align__(16) u16 vbuf[2][64 * 64];
  __shared__ __align__(16) u16 plds[4][16 * 64];
  const int tid = threadIdx.x, wid = tid >> 6, lane = tid & 63;
  const int l15 = lane & 15, lgp = lane >> 4;
  const int bh = blockIdx.y, b = bh >> 4, h = bh & 15;
  const u16* Qh = Qp + (size_t)bh * TSEQ * HD;
  const u16* Kh = Kp + (size_t)bh * TSEQ * HD;
  const u16* Vh = Vt + (size_t)bh * HD * TSEQ;
  const float* fb = frac + b * TSEQ;
  const float bs = bsum[0];                    // bias_sum * scale * log2e (pre-folded)
  const float THR2 = 24.0f;                    // defer-max threshold (log2 units)
  const int q0 = blockIdx.x * 64 + wid * 16;

  // staging lane constants (pre-swizzled global source, rule #21)
  const int srow = lane >> 3;
  const int sg8 = ((lane & 7) ^ srow) * 8;
  const int rbase = wid * 8 + srow;

  // frag-read offsets (u16 units)
  const int ofs0 = l15 * 64 + ((lgp ^ (l15 & 7)) * 8);
  const int ofs1 = l15 * 64 + (((4 + lgp) ^ (l15 & 7)) * 8);

  // Q fragments (B-operand: lane l15 = q col, lgp*8 = dh slice)
  s16x8 qf[2];
#pragma unroll
  for (int ks = 0; ks < 2; ++ks)
    qf[ks] = *(const s16x8*)(Qh + (size_t)(q0 + l15) * HD + ks * 32 + lgp * 8);

  const float fi = fb[q0 + l15];
  const float nbfi = -bs * fi;
  float m2run = -1e30f;
  float lsum = 0.f;   // per-lane partial (reduced across lgp at the end)
  f32x4 o[4];
#pragma unroll
  for (int nd = 0; nd < 4; ++nd) o[nd] = (f32x4){0.f, 0.f, 0.f, 0.f};

  auto stage = [&](int buf, int t) {
    int kv0s = t * 64;
#pragma unroll
    for (int i = 0; i < 2; ++i) {
      int row = i * 32 + rbase;
      gload16(Kh + (size_t)(kv0s + row) * HD + sg8, &kbuf[buf][i * 2048 + wid * 512]);
      gload16(Vh + (size_t)row * TSEQ + kv0s + sg8, &vbuf[buf][i * 2048 + wid * 512]);
    }
  };

  int cur = 0;
  stage(0, 0);
  __syncthreads();

  for (int t = 0; t < TSEQ / 64; ++t) {
    const bool more = (t + 1 < TSEQ / 64);
    if (more) stage(cur ^ 1, t + 1);

    // fj for this tile (L2-hot; covered by QK ds_read+MFMA latency)
    float4 fj4[4];
#pragma unroll
    for (int n = 0; n < 4; ++n)
      fj4[n] = *(const float4*)(fb + t * 64 + n * 16 + lgp * 4);

    const u16* kb = &kbuf[cur][0];
    const u16* vb = &vbuf[cur][0];

    // ---- QK^T (swapped): s[n][r] = S_log2[kv = t*64+n*16+lgp*4+r][q0+l15]
    f32x4 s[4];
    __builtin_amdgcn_s_setprio(1);
#pragma unroll
    for (int n = 0; n < 4; ++n) {
      s16x8 kf0 = *(const s16x8*)(kb + n * 1024 + ofs0);
      s16x8 kf1 = *(const s16x8*)(kb + n * 1024 + ofs1);
      f32x4 a = (f32x4){0.f, 0.f, 0.f, 0.f};
      a = __builtin_amdgcn_mfma_f32_16x16x32_bf16(kf0, qf[0], a, 0, 0, 0);
      a = __builtin_amdgcn_mfma_f32_16x16x32_bf16(kf1, qf[1], a, 0, 0, 0);
      s[n] = a;
    }
    __builtin_amdgcn_s_setprio(0);

    // ---- logits (log2 domain): l2 = s + bs*(fj-fi)/(fi*fj+eps)
    float pmax = -1e30f;
#pragma unroll
    for (int n = 0; n < 4; ++n) {
#pragma unroll
      for (int r = 0; r < 4; ++r) {
        float fj = (r == 0) ? fj4[n].x : (r == 1) ? fj4[n].y : (r == 2) ? fj4[n].z : fj4[n].w;
        float num = __builtin_fmaf(bs, fj, nbfi);
        float den = __builtin_fmaf(fi, fj, 1e-8f);
        float l2 = __builtin_fmaf(num, rcpfast(den), s[n][r]);
        s[n][r] = l2;
        pmax = fmaxf(pmax, l2);
      }
    }

    // ---- rare rescale (speculative defer-max: common path has NO shuffles)
    if (__any((pmax - m2run) > THR2)) {
      float tm = fmaxf(pmax, __shfl_xor(pmax, 16));
      tm = fmaxf(tm, __shfl_xor(tm, 32));
      float m2n = fmaxf(m2run, tm);
      float alpha = exp2fast(m2run - m2n);
      lsum *= alpha;
      m2run = m2n;
      float af[4];
#pragma unroll
      for (int r = 0; r < 4; ++r) af[r] = __shfl(alpha, lgp * 4 + r);
#pragma unroll
      for (int nd = 0; nd < 4; ++nd)
#pragma unroll
        for (int r = 0; r < 4; ++r) o[nd][r] *= af[r];
    }

    // ---- P = exp2(l2 - m2run), pack bf16, partial row-sum
    u32 w[4][2];
    {
      float ps = 0.f;
#pragma unroll
      for (int n = 0; n < 4; ++n) {
#pragma unroll
        for (int s2 = 0; s2 < 2; ++s2) {
          float p0 = exp2fast(s[n][2 * s2 + 0] - m2run);
          float p1 = exp2fast(s[n][2 * s2 + 1] - m2run);
          ps += p0 + p1;
          w[n][s2] = cvtpk(p0, p1);
        }
      }
      lsum += ps;
    }

    // ---- P -> per-wave LDS (swizzled, conflict-free) -> A-operand frags
    u16* pw = &plds[wid][0];
#pragma unroll
    for (int n = 0; n < 4; ++n) {
      int idx = l15 * 64 + ((n * 16 + lgp * 4) ^ ((l15 & 7) << 3));
      *(u32x2*)(pw + idx) = (u32x2){w[n][0], w[n][1]};
    }
    s16x8 pf[2];
#pragma unroll
    for (int ks = 0; ks < 2; ++ks) {
      int idx = l15 * 64 + ((ks * 32 + lgp * 8) ^ ((l15 & 7) << 3));
      pf[ks] = *(const s16x8*)(pw + idx);
    }

    // ---- PV: o[nd] += P * V
    __builtin_amdgcn_s_setprio(1);
#pragma unroll
    for (int nd = 0; nd < 4; ++nd) {
      s16x8 vf0 = *(const s16x8*)(vb + nd * 1024 + ofs0);
      s16x8 vf1 = *(const s16x8*)(vb + nd * 1024 + ofs1);
      o[nd] = __builtin_amdgcn_mfma_f32_16x16x32_bf16(pf[0], vf0, o[nd], 0, 0, 0);
      o[nd] = __builtin_amdgcn_mfma_f32_16x16x32_bf16(pf[1], vf1, o[nd], 0, 0, 0);
    }
    __builtin_amdgcn_s_setprio(0);

    __syncthreads();
    cur ^= 1;
  }

  // ---- finalize: reduce lsum across lgp, broadcast 1/l to o-rows, store bf16
  {
    float l = lsum;
    l += __shfl_xor(l, 16);
    l += __shfl_xor(l, 32);
    float rl[4];
#pragma unroll
    for (int r = 0; r < 4; ++r) rl[r] = __fdividef(1.f, __shfl(l, lgp * 4 + r));
#pragma unroll
    for (int nd = 0; nd < 4; ++nd)
#pragma unroll
      for (int r = 0; r < 4; ++r) {
        int q = q0 + lgp * 4 + r;
        aout[((size_t)(b * TSEQ + q)) * D_MODEL + h * HD + nd * 16 + l15] = f2bf(o[nd][r] * rl[r]);
      }
  }
}

extern "C" void kernel_launch(void* const* d_in, const int* in_sizes, int n_in,
                              void* d_out, int out_size, void* d_ws, size_t ws_size,
                              hipStream_t stream) {
  const float* query = (const float*)d_in[0];
  const float* key_  = (const float*)d_in[1];
  const float* value = (const float*)d_in[2];
  const float* frac  = (const float*)d_in[3];
  const float* Wq    = (const float*)d_in[4];
  const float* bq    = (const float*)d_in[5];
  const float* Wk    = (const float*)d_in[6];
  const float* bk    = (const float*)d_in[7];
  const float* Wv    = (const float*)d_in[8];
  const float* bv    = (const float*)d_in[9];
  const float* abias = (const float*)d_in[10];
  const float* Wo    = (const float*)d_in[11];
  const float* bo    = (const float*)d_in[12];

  char* ws = (char*)d_ws;
  size_t off = 0;
  auto alloc = [&](size_t bytes) { char* p = ws + off; off += (bytes + 255) & ~255ULL; return p; };
  const size_t XB = (size_t)MROWS * D_MODEL * 2;
  const size_t WB = (size_t)D_MODEL * D_MODEL * 2;
  u16* qb  = (u16*)alloc(XB);
  u16* kb  = (u16*)alloc(XB);
  u16* vb  = (u16*)alloc(XB);
  u16* Wqb = (u16*)alloc(WB);
  u16* Wkb = (u16*)alloc(WB);
  u16* Wvb = (u16*)alloc(WB);
  u16* Wob = (u16*)alloc(WB);
  float* bsum = (float*)alloc(256);
  u16* Qp  = (u16*)alloc(XB);
  u16* Kp  = (u16*)alloc(XB);
  u16* Vtp = (u16*)alloc(XB);
  u16* AO  = (u16*)alloc(XB);

  cvt_all<<<dim3(16385), dim3(256), 0, stream>>>(query, key_, value, Wq, Wk, Wv, Wo, abias,
                                                 qb, kb, vb, Wqb, Wkb, Wvb, Wob, bsum);

  gemm_qkv<<<dim3(D_MODEL / 128, MROWS / 128, 3), dim3(256), 0, stream>>>(
      qb, kb, vb, Wqb, Wkb, Wvb, bq, bk, bv, Qp, Kp, Vtp);

  attn_kernel<<<dim3(TSEQ / 64, NB * NHEAD), dim3(256), 0, stream>>>(Qp, Kp, Vtp, frac, bsum, AO);

  gemm_out<<<dim3(D_MODEL / 128, MROWS / 64), dim3(256), 0, stream>>>(AO, Wob, bo, (float*)d_out);
}